// Round 1
// baseline (905.439 us; speedup 1.0000x reference)
//
#include <hip/hip_runtime.h>

#define T_LEN 2048
#define B_SZ  8192
#define H     16
#define EPSC  1e-5f
#define LOG2E 1.4426950408889634f

__device__ __forceinline__ float fexp2(float x){ float r; asm("v_exp_f32 %0, %1" : "=v"(r) : "v"(x)); return r; }
__device__ __forceinline__ float frcp (float x){ float r; asm("v_rcp_f32 %0, %1" : "=v"(r) : "v"(x)); return r; }

// ---------------- Kernel A: per-timestep partial sums of x and x^2 -----------
// grid (8, 64) x 256 threads. Thread owns one t, loops 128 b's (coalesced in t).
__global__ __launch_bounds__(256) void k_stats(const float* __restrict__ x,
                                               float* __restrict__ part_s,
                                               float* __restrict__ part_q){
    int t  = blockIdx.x * 256 + threadIdx.x;
    int b0 = blockIdx.y * 128;
    const float* xp = x + (size_t)b0 * T_LEN + t;
    float s = 0.f, q = 0.f;
    #pragma unroll 4
    for (int i = 0; i < 128; ++i){
        float v = xp[(size_t)i * T_LEN];
        s += v; q = fmaf(v, v, q);
    }
    part_s[blockIdx.y * T_LEN + t] = s;
    part_q[blockIdx.y * T_LEN + t] = q;
}

// ---------------- Kernel B: BN coefficients A_t, B_t -------------------------
__global__ __launch_bounds__(256) void k_coeff(const float* __restrict__ part_s,
                                               const float* __restrict__ part_q,
                                               const float* __restrict__ fc1_w,
                                               const float* __restrict__ bn_g,
                                               const float* __restrict__ bn_b,
                                               float2* __restrict__ AB){
    int t = blockIdx.x * 256 + threadIdx.x;
    float s = 0.f, q = 0.f;
    for (int i = 0; i < 64; ++i){
        s += part_s[i * T_LEN + t];
        q += part_q[i * T_LEN + t];
    }
    float mu  = s * (1.f / B_SZ);
    float var = fmaf(-mu, mu, q * (1.f / B_SZ));   // biased var of x
    float w   = fc1_w[0];
    float rs  = rsqrtf(fmaf(w * w, var, EPSC));    // rsqrt(var_f + eps), fc1_b cancels
    float A   = bn_g[0] * rs * w;
    float Bc  = bn_b[0] - A * mu;
    AB[t] = make_float2(A, Bc);
}

// ---------------- Kernel D: fused LSTM + fc2 + softmax -----------------------
// 16 lanes per batch element: lane j in [0,16) owns h[j], c[j] and gate rows
// j, j+16, j+32, j+48 (weights stationary in 64 VGPRs). 4 b per wave,
// 2048 waves total = 2 waves/SIMD. Gate rows pre-scaled so activations are
// exp2/rcp only.
__global__ __launch_bounds__(256, 2) void k_lstm(
    const float* __restrict__ x, const float2* __restrict__ AB,
    const float* __restrict__ w_ih, const float* __restrict__ w_hh,
    const float* __restrict__ b_ih, const float* __restrict__ b_hh,
    const float* __restrict__ fc2_w, const float* __restrict__ fc2_b,
    float* __restrict__ out)
{
    __shared__ float2 sAB[T_LEN];
    int tid = threadIdx.x;
    #pragma unroll
    for (int i = 0; i < T_LEN / 256; ++i) sAB[i * 256 + tid] = AB[i * 256 + tid];
    __syncthreads();

    int lane = tid & 63;
    int wave = tid >> 6;
    int g    = lane >> 4;          // batch element within wave (0..3)
    int j    = lane & 15;          // hidden index owned by this lane
    int b    = (blockIdx.x * 4 + wave) * 4 + g;

    // stationary weights (pre-scaled: sigmoid rows * -log2e, tanh rows * 2log2e)
    float wi[H], wf[H], wg[H], wo[H];
    #pragma unroll
    for (int k = 0; k < H; ++k){
        wi[k] = w_hh[(0 * H + j) * H + k] * (-LOG2E);
        wf[k] = w_hh[(1 * H + j) * H + k] * (-LOG2E);
        wg[k] = w_hh[(2 * H + j) * H + k] * (2.f * LOG2E);
        wo[k] = w_hh[(3 * H + j) * H + k] * (-LOG2E);
    }
    float ai = w_ih[0 * H + j] * (-LOG2E);
    float af = w_ih[1 * H + j] * (-LOG2E);
    float ag = w_ih[2 * H + j] * (2.f * LOG2E);
    float ao = w_ih[3 * H + j] * (-LOG2E);
    float bi = (b_ih[0 * H + j] + b_hh[0 * H + j]) * (-LOG2E);
    float bf = (b_ih[1 * H + j] + b_hh[1 * H + j]) * (-LOG2E);
    float bg = (b_ih[2 * H + j] + b_hh[2 * H + j]) * (2.f * LOG2E);
    float bo = (b_ih[3 * H + j] + b_hh[3 * H + j]) * (-LOG2E);

    float h = 0.f, c = 0.f;
    const float* xp = x + (size_t)b * T_LEN;

    for (int t = 0; t < T_LEN; ++t){
        float2 ab = sAB[t];
        float ft = fmaxf(fmaf(ab.x, xp[t], ab.y), 0.f);   // BN + ReLU on the fly

        float acc_i = fmaf(ft, ai, bi);
        float acc_f = fmaf(ft, af, bf);
        float acc_g = fmaf(ft, ag, bg);
        float acc_o = fmaf(ft, ao, bo);

        #pragma unroll
        for (int k = 0; k < H; ++k){
            float hk = __shfl(h, k, 16);
            acc_i = fmaf(wi[k], hk, acc_i);
            acc_f = fmaf(wf[k], hk, acc_f);
            acc_g = fmaf(wg[k], hk, acc_g);
            acc_o = fmaf(wo[k], hk, acc_o);
        }

        float si = frcp(1.f + fexp2(acc_i));                    // sigmoid(i)
        float sf = frcp(1.f + fexp2(acc_f));                    // sigmoid(f)
        float tg = fmaf(-2.f, frcp(1.f + fexp2(acc_g)), 1.f);   // tanh(g)
        float so = frcp(1.f + fexp2(acc_o));                    // sigmoid(o)

        c = fmaf(sf, c, si * tg);
        float tc = fmaf(-2.f, frcp(1.f + fexp2(c * (2.f * LOG2E))), 1.f); // tanh(c)
        h = so * tc;
    }

    // fc2 (2x16) + softmax: reduce h over the 16-lane group
    float l0 = h * fc2_w[0 * H + j];
    float l1 = h * fc2_w[1 * H + j];
    #pragma unroll
    for (int o = 8; o >= 1; o >>= 1){
        l0 += __shfl_xor(l0, o, 16);
        l1 += __shfl_xor(l1, o, 16);
    }
    if (j == 0){
        l0 += fc2_b[0];
        l1 += fc2_b[1];
        float p1 = frcp(1.f + fexp2((l0 - l1) * LOG2E));  // 1/(1+e^{l0-l1})
        out[2 * b + 0] = 1.f - p1;
        out[2 * b + 1] = p1;
    }
}

extern "C" void kernel_launch(void* const* d_in, const int* in_sizes, int n_in,
                              void* d_out, int out_size, void* d_ws, size_t ws_size,
                              hipStream_t stream){
    const float* x     = (const float*)d_in[0];
    const float* fc1_w = (const float*)d_in[1];
    // d_in[2] = fc1_b: cancels out of the BN algebra, unused
    const float* bn_g  = (const float*)d_in[3];
    const float* bn_b  = (const float*)d_in[4];
    const float* w_ih  = (const float*)d_in[5];
    const float* w_hh  = (const float*)d_in[6];
    const float* b_ih  = (const float*)d_in[7];
    const float* b_hh  = (const float*)d_in[8];
    const float* fc2_w = (const float*)d_in[9];
    const float* fc2_b = (const float*)d_in[10];
    float* out = (float*)d_out;

    float* ws     = (float*)d_ws;
    float* part_s = ws;                       // 64*2048 f32
    float* part_q = ws + 64 * T_LEN;          // 64*2048 f32
    float2* AB    = (float2*)(ws + 128 * T_LEN); // 2048 float2

    k_stats<<<dim3(T_LEN / 256, 64), 256, 0, stream>>>(x, part_s, part_q);
    k_coeff<<<dim3(T_LEN / 256), 256, 0, stream>>>(part_s, part_q, fc1_w, bn_g, bn_b, AB);
    k_lstm <<<dim3(B_SZ / 16), 256, 0, stream>>>(x, AB, w_ih, w_hh, b_ih, b_hh,
                                                 fc2_w, fc2_b, out);
}

// Round 2
// 679.344 us; speedup vs baseline: 1.3328x; 1.3328x over previous
//
#include <hip/hip_runtime.h>

#define T_LEN 2048
#define B_SZ  8192
#define H     16
#define EPSC  1e-5f
#define LOG2E 1.4426950408889634f

__device__ __forceinline__ float fexp2(float x){ float r; asm("v_exp_f32 %0, %1" : "=v"(r) : "v"(x)); return r; }
__device__ __forceinline__ float frcp (float x){ float r; asm("v_rcp_f32 %0, %1" : "=v"(r) : "v"(x)); return r; }

// ---------------- Kernel A: per-timestep partial sums of x and x^2 -----------
__global__ __launch_bounds__(256) void k_stats(const float* __restrict__ x,
                                               float* __restrict__ part_s,
                                               float* __restrict__ part_q){
    int t  = blockIdx.x * 256 + threadIdx.x;
    int b0 = blockIdx.y * 128;
    const float* xp = x + (size_t)b0 * T_LEN + t;
    float s = 0.f, q = 0.f;
    #pragma unroll 4
    for (int i = 0; i < 128; ++i){
        float v = xp[(size_t)i * T_LEN];
        s += v; q = fmaf(v, v, q);
    }
    part_s[blockIdx.y * T_LEN + t] = s;
    part_q[blockIdx.y * T_LEN + t] = q;
}

// ---------------- Kernel B: BN coefficients A_t, B_t -------------------------
__global__ __launch_bounds__(256) void k_coeff(const float* __restrict__ part_s,
                                               const float* __restrict__ part_q,
                                               const float* __restrict__ fc1_w,
                                               const float* __restrict__ bn_g,
                                               const float* __restrict__ bn_b,
                                               float2* __restrict__ AB){
    int t = blockIdx.x * 256 + threadIdx.x;
    float s = 0.f, q = 0.f;
    for (int i = 0; i < 64; ++i){
        s += part_s[i * T_LEN + t];
        q += part_q[i * T_LEN + t];
    }
    float mu  = s * (1.f / B_SZ);
    float var = fmaf(-mu, mu, q * (1.f / B_SZ));   // biased var of x
    float w   = fc1_w[0];
    float rs  = rsqrtf(fmaf(w * w, var, EPSC));    // rsqrt(var_f + eps), fc1_b cancels
    float A   = bn_g[0] * rs * w;
    float Bc  = bn_b[0] - A * mu;
    AB[t] = make_float2(A, Bc);
}

// ---------------- Kernel D: fused LSTM + fc2 + softmax -----------------------
// 16 lanes per batch element; lane j owns h[j], c[j] and gate rows j,j+16,j+32,
// j+48 (weights stationary, packed as float2 over k). h is exchanged via a
// per-group LDS row: 1 ds_write_b32 + 4 ds_read_b128 per step, all addresses
// loop-invariant (no per-step shuffle address math). t-loop unrolled x4 with a
// single float4 x load per 4 steps.
__global__ __launch_bounds__(256, 2) void k_lstm(
    const float* __restrict__ x, const float2* __restrict__ AB,
    const float* __restrict__ w_ih, const float* __restrict__ w_hh,
    const float* __restrict__ b_ih, const float* __restrict__ b_hh,
    const float* __restrict__ fc2_w, const float* __restrict__ fc2_b,
    float* __restrict__ out)
{
    __shared__ float2 sAB[T_LEN];      // 16 KB
    __shared__ float  sH[16][16];      // 1 KB: [group][j]
    int tid = threadIdx.x;
    #pragma unroll
    for (int i = 0; i < T_LEN / 256; ++i) sAB[i * 256 + tid] = AB[i * 256 + tid];
    __syncthreads();

    int lane = tid & 63;
    int wave = tid >> 6;
    int g    = lane >> 4;          // group within wave (0..3)
    int j    = lane & 15;          // hidden index owned by this lane
    int grp  = wave * 4 + g;       // group within block (0..15)
    int b    = blockIdx.x * 16 + grp;

    // stationary weights (pre-scaled: sigmoid rows * -log2e, tanh rows * 2log2e)
    float2 wi2[8], wf2[8], wg2[8], wo2[8];
    #pragma unroll
    for (int k2 = 0; k2 < 8; ++k2){
        wi2[k2] = make_float2(w_hh[(0*H + j)*H + 2*k2] * (-LOG2E),
                              w_hh[(0*H + j)*H + 2*k2 + 1] * (-LOG2E));
        wf2[k2] = make_float2(w_hh[(1*H + j)*H + 2*k2] * (-LOG2E),
                              w_hh[(1*H + j)*H + 2*k2 + 1] * (-LOG2E));
        wg2[k2] = make_float2(w_hh[(2*H + j)*H + 2*k2] * (2.f*LOG2E),
                              w_hh[(2*H + j)*H + 2*k2 + 1] * (2.f*LOG2E));
        wo2[k2] = make_float2(w_hh[(3*H + j)*H + 2*k2] * (-LOG2E),
                              w_hh[(3*H + j)*H + 2*k2 + 1] * (-LOG2E));
    }
    float ai = w_ih[0*H + j] * (-LOG2E);
    float af = w_ih[1*H + j] * (-LOG2E);
    float ag = w_ih[2*H + j] * (2.f*LOG2E);
    float ao = w_ih[3*H + j] * (-LOG2E);
    float bi = (b_ih[0*H + j] + b_hh[0*H + j]) * (-LOG2E);
    float bf = (b_ih[1*H + j] + b_hh[1*H + j]) * (-LOG2E);
    float bg = (b_ih[2*H + j] + b_hh[2*H + j]) * (2.f*LOG2E);
    float bo = (b_ih[3*H + j] + b_hh[3*H + j]) * (-LOG2E);

    float h = 0.f, c = 0.f;
    const float* xp   = x + (size_t)b * T_LEN;
    float*       hrow = &sH[grp][0];

    for (int t0 = 0; t0 < T_LEN; t0 += 4){
        float4 xv = *(const float4*)(xp + t0);
        #pragma unroll
        for (int u = 0; u < 4; ++u){
            float xt = (u == 0) ? xv.x : (u == 1) ? xv.y : (u == 2) ? xv.z : xv.w;
            float2 ab = sAB[t0 + u];
            float ft = fmaxf(fmaf(ab.x, xt, ab.y), 0.f);   // BN + ReLU

            hrow[j] = h;                                   // ds_write_b32 (fixed addr)

            float acc_i = fmaf(ft, ai, bi);
            float acc_f = fmaf(ft, af, bf);
            float acc_g = fmaf(ft, ag, bg);
            float acc_o = fmaf(ft, ao, bo);

            float2 hv[8];
            *(float4*)&hv[0] = *(const float4*)&hrow[0];   // 4x ds_read_b128
            *(float4*)&hv[2] = *(const float4*)&hrow[4];   //   (fixed addrs,
            *(float4*)&hv[4] = *(const float4*)&hrow[8];   //    broadcast reads)
            *(float4*)&hv[6] = *(const float4*)&hrow[12];

            // two independent 8-deep float2 chains per gate
            float2 a2i = make_float2(0.f, 0.f), a2f = a2i, a2g = a2i, a2o = a2i;
            #pragma unroll
            for (int k2 = 0; k2 < 8; ++k2){
                float2 hh = hv[k2];
                a2i.x = fmaf(wi2[k2].x, hh.x, a2i.x); a2i.y = fmaf(wi2[k2].y, hh.y, a2i.y);
                a2f.x = fmaf(wf2[k2].x, hh.x, a2f.x); a2f.y = fmaf(wf2[k2].y, hh.y, a2f.y);
                a2g.x = fmaf(wg2[k2].x, hh.x, a2g.x); a2g.y = fmaf(wg2[k2].y, hh.y, a2g.y);
                a2o.x = fmaf(wo2[k2].x, hh.x, a2o.x); a2o.y = fmaf(wo2[k2].y, hh.y, a2o.y);
            }
            acc_i += a2i.x + a2i.y;
            acc_f += a2f.x + a2f.y;
            acc_g += a2g.x + a2g.y;
            acc_o += a2o.x + a2o.y;

            float si = frcp(1.f + fexp2(acc_i));                   // sigmoid(i)
            float sf = frcp(1.f + fexp2(acc_f));                   // sigmoid(f)
            float tg = fmaf(-2.f, frcp(1.f + fexp2(acc_g)), 1.f);  // tanh(g)
            float so = frcp(1.f + fexp2(acc_o));                   // sigmoid(o)

            c = fmaf(sf, c, si * tg);
            float tc = fmaf(-2.f, frcp(1.f + fexp2(c * (2.f*LOG2E))), 1.f); // tanh(c)
            h = so * tc;
        }
    }

    // fc2 (2x16) + softmax: reduce h over the 16-lane group
    float l0 = h * fc2_w[0*H + j];
    float l1 = h * fc2_w[1*H + j];
    #pragma unroll
    for (int o = 8; o >= 1; o >>= 1){
        l0 += __shfl_xor(l0, o, 16);
        l1 += __shfl_xor(l1, o, 16);
    }
    if (j == 0){
        l0 += fc2_b[0];
        l1 += fc2_b[1];
        float p1 = frcp(1.f + fexp2((l0 - l1) * LOG2E));  // softmax, 2 classes
        out[2*b + 0] = 1.f - p1;
        out[2*b + 1] = p1;
    }
}

extern "C" void kernel_launch(void* const* d_in, const int* in_sizes, int n_in,
                              void* d_out, int out_size, void* d_ws, size_t ws_size,
                              hipStream_t stream){
    const float* x     = (const float*)d_in[0];
    const float* fc1_w = (const float*)d_in[1];
    // d_in[2] = fc1_b: cancels out of the BN algebra, unused
    const float* bn_g  = (const float*)d_in[3];
    const float* bn_b  = (const float*)d_in[4];
    const float* w_ih  = (const float*)d_in[5];
    const float* w_hh  = (const float*)d_in[6];
    const float* b_ih  = (const float*)d_in[7];
    const float* b_hh  = (const float*)d_in[8];
    const float* fc2_w = (const float*)d_in[9];
    const float* fc2_b = (const float*)d_in[10];
    float* out = (float*)d_out;

    float* ws     = (float*)d_ws;
    float* part_s = ws;                          // 64*2048 f32
    float* part_q = ws + 64 * T_LEN;             // 64*2048 f32
    float2* AB    = (float2*)(ws + 128 * T_LEN); // 2048 float2

    k_stats<<<dim3(T_LEN / 256, 64), 256, 0, stream>>>(x, part_s, part_q);
    k_coeff<<<dim3(T_LEN / 256), 256, 0, stream>>>(part_s, part_q, fc1_w, bn_g, bn_b, AB);
    k_lstm <<<dim3(B_SZ / 16), 256, 0, stream>>>(x, AB, w_ih, w_hh, b_ih, b_hh,
                                                 fc2_w, fc2_b, out);
}

// Round 3
// 628.303 us; speedup vs baseline: 1.4411x; 1.0812x over previous
//
#include <hip/hip_runtime.h>

#define T_LEN 2048
#define B_SZ  8192
#define H     16
#define EPSC  1e-5f
#define LOG2E 1.4426950408889634f

__device__ __forceinline__ float fexp2(float x){ float r; asm("v_exp_f32 %0, %1" : "=v"(r) : "v"(x)); return r; }
__device__ __forceinline__ float frcp (float x){ float r; asm("v_rcp_f32 %0, %1" : "=v"(r) : "v"(x)); return r; }
// packed 2xbf16 dot with f32 accumulate: acc += a.lo*b.lo + a.hi*b.hi
__device__ __forceinline__ void dot2c(float& acc, unsigned a, unsigned b){
    asm("v_dot2c_f32_bf16 %0, %1, %2" : "+v"(acc) : "v"(a), "v"(b));
}
__device__ __forceinline__ unsigned cvtpk_bf16(float a, float b){
    unsigned r; asm("v_cvt_pk_bf16_f32 %0, %1, %2" : "=v"(r) : "v"(a), "v"(b)); return r;
}
// host-side-quality RNE f32->bf16 for init-time weight packing
__device__ __forceinline__ unsigned short f2bf(float f){
    union { float f; unsigned u; } v; v.f = f;
    return (unsigned short)((v.u + 0x7fffu + ((v.u >> 16) & 1u)) >> 16);
}

// ---------------- Kernel A: per-timestep partial sums of x and x^2 -----------
__global__ __launch_bounds__(256) void k_stats(const float* __restrict__ x,
                                               float* __restrict__ part_s,
                                               float* __restrict__ part_q){
    int t  = blockIdx.x * 256 + threadIdx.x;
    int b0 = blockIdx.y * 128;
    const float* xp = x + (size_t)b0 * T_LEN + t;
    float s = 0.f, q = 0.f;
    #pragma unroll 4
    for (int i = 0; i < 128; ++i){
        float v = xp[(size_t)i * T_LEN];
        s += v; q = fmaf(v, v, q);
    }
    part_s[blockIdx.y * T_LEN + t] = s;
    part_q[blockIdx.y * T_LEN + t] = q;
}

// ---------------- Kernel B: BN coefficients A_t, B_t -------------------------
__global__ __launch_bounds__(256) void k_coeff(const float* __restrict__ part_s,
                                               const float* __restrict__ part_q,
                                               const float* __restrict__ fc1_w,
                                               const float* __restrict__ bn_g,
                                               const float* __restrict__ bn_b,
                                               float2* __restrict__ AB){
    int t = blockIdx.x * 256 + threadIdx.x;
    float s = 0.f, q = 0.f;
    for (int i = 0; i < 64; ++i){
        s += part_s[i * T_LEN + t];
        q += part_q[i * T_LEN + t];
    }
    float mu  = s * (1.f / B_SZ);
    float var = fmaf(-mu, mu, q * (1.f / B_SZ));   // biased var of x
    float w   = fc1_w[0];
    float rs  = rsqrtf(fmaf(w * w, var, EPSC));    // rsqrt(var_f + eps), fc1_b cancels
    float A   = bn_g[0] * rs * w;
    float Bc  = bn_b[0] - A * mu;
    AB[t] = make_float2(A, Bc);
}

// ---------------- Kernel D: fused LSTM + fc2 + softmax -----------------------
// 16 lanes per batch element; lane j owns h[j], c[j] and gate rows j,j+16,j+32,
// j+48. W_hh rows pre-scaled and packed as bf16 pairs (8 dwords/gate/lane).
// h exchanged via LDS as bf16: 1 ds_write_b16 + 2 ds_read_b128 per step; dots
// via v_dot2c_f32_bf16 (32 insts vs 64 f32 FMAs). x-term + biases stay f32.
__global__ __launch_bounds__(256, 2) void k_lstm(
    const float* __restrict__ x, const float2* __restrict__ AB,
    const float* __restrict__ w_ih, const float* __restrict__ w_hh,
    const float* __restrict__ b_ih, const float* __restrict__ b_hh,
    const float* __restrict__ fc2_w, const float* __restrict__ fc2_b,
    float* __restrict__ out)
{
    __shared__ float2 sAB[T_LEN];                 // 16 KB
    __shared__ unsigned short sH[16][16];         // 512 B: [group][j] bf16
    int tid = threadIdx.x;
    #pragma unroll
    for (int i = 0; i < T_LEN / 256; ++i) sAB[i * 256 + tid] = AB[i * 256 + tid];
    __syncthreads();

    int lane = tid & 63;
    int wave = tid >> 6;
    int g    = lane >> 4;          // group within wave (0..3)
    int j    = lane & 15;          // hidden index owned by this lane
    int grp  = wave * 4 + g;       // group within block (0..15)
    int b    = blockIdx.x * 16 + grp;

    // stationary packed weights: wp[gate][k2] = {bf16(w[2k2]), bf16(w[2k2+1])}
    // pre-scaled: sigmoid rows * -log2e, tanh row * 2log2e
    unsigned wp0[8], wp1[8], wp2[8], wp3[8];
    #pragma unroll
    for (int k2 = 0; k2 < 8; ++k2){
        const float s0 = -LOG2E, s2 = 2.f * LOG2E;
        wp0[k2] = (unsigned)f2bf(w_hh[(0*H + j)*H + 2*k2] * s0)
                | ((unsigned)f2bf(w_hh[(0*H + j)*H + 2*k2 + 1] * s0) << 16);
        wp1[k2] = (unsigned)f2bf(w_hh[(1*H + j)*H + 2*k2] * s0)
                | ((unsigned)f2bf(w_hh[(1*H + j)*H + 2*k2 + 1] * s0) << 16);
        wp2[k2] = (unsigned)f2bf(w_hh[(2*H + j)*H + 2*k2] * s2)
                | ((unsigned)f2bf(w_hh[(2*H + j)*H + 2*k2 + 1] * s2) << 16);
        wp3[k2] = (unsigned)f2bf(w_hh[(3*H + j)*H + 2*k2] * s0)
                | ((unsigned)f2bf(w_hh[(3*H + j)*H + 2*k2 + 1] * s0) << 16);
    }
    float ai = w_ih[0*H + j] * (-LOG2E);
    float af = w_ih[1*H + j] * (-LOG2E);
    float ag = w_ih[2*H + j] * (2.f*LOG2E);
    float ao = w_ih[3*H + j] * (-LOG2E);
    float bi = (b_ih[0*H + j] + b_hh[0*H + j]) * (-LOG2E);
    float bf = (b_ih[1*H + j] + b_hh[1*H + j]) * (-LOG2E);
    float bg = (b_ih[2*H + j] + b_hh[2*H + j]) * (2.f*LOG2E);
    float bo = (b_ih[3*H + j] + b_hh[3*H + j]) * (-LOG2E);

    float h = 0.f, c = 0.f;
    const float* xp = x + (size_t)b * T_LEN;
    unsigned short* hrow = &sH[grp][0];

    for (int t0 = 0; t0 < T_LEN; t0 += 4){
        float4 xv = *(const float4*)(xp + t0);
        #pragma unroll
        for (int u = 0; u < 4; ++u){
            float xt = (u == 0) ? xv.x : (u == 1) ? xv.y : (u == 2) ? xv.z : xv.w;
            float2 ab = sAB[t0 + u];
            float ft = fmaxf(fmaf(ab.x, xt, ab.y), 0.f);   // BN + ReLU

            hrow[j] = (unsigned short)cvtpk_bf16(h, h);    // ds_write_b16

            float acc_i = fmaf(ft, ai, bi);
            float acc_f = fmaf(ft, af, bf);
            float acc_g = fmaf(ft, ag, bg);
            float acc_o = fmaf(ft, ao, bo);

            uint4 r0 = *(const uint4*)&hrow[0];            // h0..h7  (bf16 pairs)
            uint4 r1 = *(const uint4*)&hrow[8];            // h8..h15

            dot2c(acc_i, wp0[0], r0.x); dot2c(acc_i, wp0[1], r0.y);
            dot2c(acc_i, wp0[2], r0.z); dot2c(acc_i, wp0[3], r0.w);
            dot2c(acc_i, wp0[4], r1.x); dot2c(acc_i, wp0[5], r1.y);
            dot2c(acc_i, wp0[6], r1.z); dot2c(acc_i, wp0[7], r1.w);

            dot2c(acc_f, wp1[0], r0.x); dot2c(acc_f, wp1[1], r0.y);
            dot2c(acc_f, wp1[2], r0.z); dot2c(acc_f, wp1[3], r0.w);
            dot2c(acc_f, wp1[4], r1.x); dot2c(acc_f, wp1[5], r1.y);
            dot2c(acc_f, wp1[6], r1.z); dot2c(acc_f, wp1[7], r1.w);

            dot2c(acc_g, wp2[0], r0.x); dot2c(acc_g, wp2[1], r0.y);
            dot2c(acc_g, wp2[2], r0.z); dot2c(acc_g, wp2[3], r0.w);
            dot2c(acc_g, wp2[4], r1.x); dot2c(acc_g, wp2[5], r1.y);
            dot2c(acc_g, wp2[6], r1.z); dot2c(acc_g, wp2[7], r1.w);

            dot2c(acc_o, wp3[0], r0.x); dot2c(acc_o, wp3[1], r0.y);
            dot2c(acc_o, wp3[2], r0.z); dot2c(acc_o, wp3[3], r0.w);
            dot2c(acc_o, wp3[4], r1.x); dot2c(acc_o, wp3[5], r1.y);
            dot2c(acc_o, wp3[6], r1.z); dot2c(acc_o, wp3[7], r1.w);

            float si = frcp(1.f + fexp2(acc_i));                   // sigmoid(i)
            float sf = frcp(1.f + fexp2(acc_f));                   // sigmoid(f)
            float tg = fmaf(-2.f, frcp(1.f + fexp2(acc_g)), 1.f);  // tanh(g)
            float so = frcp(1.f + fexp2(acc_o));                   // sigmoid(o)

            c = fmaf(sf, c, si * tg);
            float tc = fmaf(-2.f, frcp(1.f + fexp2(c * (2.f*LOG2E))), 1.f); // tanh(c)
            h = so * tc;
        }
    }

    // fc2 (2x16) + softmax: reduce h over the 16-lane group
    float l0 = h * fc2_w[0*H + j];
    float l1 = h * fc2_w[1*H + j];
    #pragma unroll
    for (int o = 8; o >= 1; o >>= 1){
        l0 += __shfl_xor(l0, o, 16);
        l1 += __shfl_xor(l1, o, 16);
    }
    if (j == 0){
        l0 += fc2_b[0];
        l1 += fc2_b[1];
        float p1 = frcp(1.f + fexp2((l0 - l1) * LOG2E));  // softmax, 2 classes
        out[2*b + 0] = 1.f - p1;
        out[2*b + 1] = p1;
    }
}

extern "C" void kernel_launch(void* const* d_in, const int* in_sizes, int n_in,
                              void* d_out, int out_size, void* d_ws, size_t ws_size,
                              hipStream_t stream){
    const float* x     = (const float*)d_in[0];
    const float* fc1_w = (const float*)d_in[1];
    // d_in[2] = fc1_b: cancels out of the BN algebra, unused
    const float* bn_g  = (const float*)d_in[3];
    const float* bn_b  = (const float*)d_in[4];
    const float* w_ih  = (const float*)d_in[5];
    const float* w_hh  = (const float*)d_in[6];
    const float* b_ih  = (const float*)d_in[7];
    const float* b_hh  = (const float*)d_in[8];
    const float* fc2_w = (const float*)d_in[9];
    const float* fc2_b = (const float*)d_in[10];
    float* out = (float*)d_out;

    float* ws     = (float*)d_ws;
    float* part_s = ws;                          // 64*2048 f32
    float* part_q = ws + 64 * T_LEN;             // 64*2048 f32
    float2* AB    = (float2*)(ws + 128 * T_LEN); // 2048 float2

    k_stats<<<dim3(T_LEN / 256, 64), 256, 0, stream>>>(x, part_s, part_q);
    k_coeff<<<dim3(T_LEN / 256), 256, 0, stream>>>(part_s, part_q, fc1_w, bn_g, bn_b, AB);
    k_lstm <<<dim3(B_SZ / 16), 256, 0, stream>>>(x, AB, w_ih, w_hh, b_ih, b_hh,
                                                 fc2_w, fc2_b, out);
}